// Round 1
// baseline (37.544 us; speedup 1.0000x reference)
//
#include <hip/hip_runtime.h>

// LocallyConnected2d: out[b,o,ho,wo] = bias[o,ho,wo]
//   + sum_{c,ki,kj} x[b,c,ho+ki,wo+kj] * w[o,c,ho,wo,ki*3+kj]
//
// Strategy: 1 thread per (o,ho,wo); batch loop innermost with 8 register
// accumulators so each weight element (70.9 MB total, the dominant HBM
// stream) is fetched exactly once. x (2 MB) is L2-resident and re-read.

#define BB 8
#define CC 16
#define HH 64
#define WW 64
#define OO 32
#define HO 62
#define WO 62

__global__ __launch_bounds__(256) void lc2d_kernel(
    const float* __restrict__ x, const float* __restrict__ weight,
    const float* __restrict__ bias, float* __restrict__ out) {
  const int total = OO * HO * WO;  // 123008
  int tid = blockIdx.x * 256 + threadIdx.x;
  if (tid >= total) return;

  const int wo = tid % WO;
  const int t  = tid / WO;
  const int ho = t % HO;
  const int o  = t / HO;

  float acc[BB];
#pragma unroll
  for (int b = 0; b < BB; ++b) acc[b] = 0.0f;

  // weight element base for (o, c=0, ho, wo): layout (O,C,HO,WO,9)
  const float* wp = weight + ((size_t)o * CC * HO * WO + (size_t)ho * WO + wo) * 9;
  // x base for (b=0, c=0, ho, wo): layout (B,C,H,W)
  const float* xp = x + ho * WW + wo;

  for (int c = 0; c < CC; ++c) {
    float wreg[9];
#pragma unroll
    for (int k = 0; k < 9; ++k) wreg[k] = wp[k];

    const float* xc = xp + c * (HH * WW);
#pragma unroll
    for (int b = 0; b < BB; ++b) {
      const float* xb = xc + b * (CC * HH * WW);
      float s0 = xb[0]      * wreg[0] + xb[1]        * wreg[1] + xb[2]        * wreg[2];
      float s1 = xb[WW]     * wreg[3] + xb[WW + 1]   * wreg[4] + xb[WW + 2]   * wreg[5];
      float s2 = xb[2 * WW] * wreg[6] + xb[2*WW + 1] * wreg[7] + xb[2*WW + 2] * wreg[8];
      acc[b] += s0 + s1 + s2;
    }
    wp += (size_t)HO * WO * 9;  // advance c
  }

  // bias flat layout (O,HO,WO) == tid enumeration
  const float bv = bias[tid];
#pragma unroll
  for (int b = 0; b < BB; ++b) {
    out[(size_t)b * total + tid] = acc[b] + bv;
  }
}

extern "C" void kernel_launch(void* const* d_in, const int* in_sizes, int n_in,
                              void* d_out, int out_size, void* d_ws, size_t ws_size,
                              hipStream_t stream) {
  const float* x = (const float*)d_in[0];
  const float* w = (const float*)d_in[1];
  const float* bias = (const float*)d_in[2];
  float* out = (float*)d_out;

  const int total = OO * HO * WO;  // 123008
  const int blocks = (total + 255) / 256;  // 481
  hipLaunchKernelGGL(lc2d_kernel, dim3(blocks), dim3(256), 0, stream,
                     x, w, bias, out);
}

// Round 3
// 31.838 us; speedup vs baseline: 1.1792x; 1.1792x over previous
//
#include <hip/hip_runtime.h>

// LocallyConnected2d: out[b,o,ho,wo] = bias[o,ho,wo]
//   + sum_{c,ki,kj} x[b,c,ho+ki,wo+kj] * w[o,c,ho,wo,ki*3+kj]
//
// Round-3: r2 structure with SOUND synchronization.
//  - block = one (o, ho) output row, 256 threads = 4 waves; wave handles
//    c in [4w, 4w+4). Weight fetched exactly once from HBM (b-loop in regs).
//  - weight row (o,c,ho,*,*) = 558 contiguous floats staged into per-wave LDS
//    region with coalesced loads.
//  - EVERY LDS write->read and read->overwrite crosses __syncthreads()
//    (r2 relied on barrier-free intra-wave DS ordering -> garbage output).
//  - x: 1 coalesced load per (c,b,row); cols wo+1, wo+2 via ds_bpermute.
//  - lanes 62/63 use clamped weight index: never read unwritten LDS.

#define BB 8
#define CC 16
#define HH 64
#define WW 64
#define OO 32
#define HO 62
#define WO 62
#define NLOC (HO * WO)    // 3844
#define TOTAL (OO * NLOC) // 123008

__global__ __launch_bounds__(256) void lc2d_kernel(
    const float* __restrict__ x, const float* __restrict__ weight,
    const float* __restrict__ bias, float* __restrict__ out) {
  __shared__ float smem[4 * 576];

  const int tid  = threadIdx.x;
  const int lane = tid & 63;
  const int wave = tid >> 6;
  const int ho = blockIdx.x % HO;
  const int o  = blockIdx.x / HO;

  float* sw = smem + wave * 576;

  // bpermute byte addresses for neighbor columns wo+1, wo+2
  const int a1 = ((lane + 1) & 63) << 2;
  const int a2 = ((lane + 2) & 63) << 2;
  // clamped weight-fragment index: lanes 62/63 read lane 61's (valid) slots
  const int lidx = (lane < WO ? lane : WO - 1) * 9;

  float acc[BB];
#pragma unroll
  for (int b = 0; b < BB; ++b) acc[b] = 0.0f;

  for (int cc = 0; cc < 4; ++cc) {
    const int c = wave * 4 + cc;

    // ---- stage weight row: 558 contiguous floats, coalesced ----
    const float* wg = weight + (size_t)(o * CC + c) * (NLOC * 9) + (size_t)ho * (WO * 9);
#pragma unroll
    for (int j = 0; j < 9; ++j) {
      int idx = j * 64 + lane;
      if (idx < WO * 9) sw[idx] = wg[idx];
    }
    __syncthreads();  // write -> read

    float wreg[9];
#pragma unroll
    for (int k = 0; k < 9; ++k) wreg[k] = sw[lidx + k];

    // ---- batch loop: 1 load/row, neighbors via bpermute ----
    const float* xc = x + (size_t)c * (HH * WW) + (size_t)ho * WW + lane;
#pragma unroll
    for (int b = 0; b < BB; ++b) {
      const float* xb = xc + (size_t)b * (CC * HH * WW);
      float v0 = xb[0];
      float v1 = xb[WW];
      float v2 = xb[2 * WW];
      float v0a = __int_as_float(__builtin_amdgcn_ds_bpermute(a1, __float_as_int(v0)));
      float v0b = __int_as_float(__builtin_amdgcn_ds_bpermute(a2, __float_as_int(v0)));
      float v1a = __int_as_float(__builtin_amdgcn_ds_bpermute(a1, __float_as_int(v1)));
      float v1b = __int_as_float(__builtin_amdgcn_ds_bpermute(a2, __float_as_int(v1)));
      float v2a = __int_as_float(__builtin_amdgcn_ds_bpermute(a1, __float_as_int(v2)));
      float v2b = __int_as_float(__builtin_amdgcn_ds_bpermute(a2, __float_as_int(v2)));
      acc[b] += v0 * wreg[0] + v0a * wreg[1] + v0b * wreg[2]
              + v1 * wreg[3] + v1a * wreg[4] + v1b * wreg[5]
              + v2 * wreg[6] + v2a * wreg[7] + v2b * wreg[8];
    }
    __syncthreads();  // read -> next iteration's (or stash's) write
  }

  // ---- stash partials into this wave's own LDS region ----
#pragma unroll
  for (int b = 0; b < BB; ++b) sw[lane * 9 + b] = acc[b];
  __syncthreads();  // stash write -> cross-wave read

  // ---- reduce 4 wave-partials, add bias, store: 512 (b,wo) pairs ----
  for (int p = tid; p < 512; p += 256) {
    int b = p >> 6;
    int l = p & 63;
    if (l < WO) {
      float s = smem[0 * 576 + l * 9 + b] + smem[1 * 576 + l * 9 + b]
              + smem[2 * 576 + l * 9 + b] + smem[3 * 576 + l * 9 + b];
      int loc = o * NLOC + ho * WO + l;
      out[(size_t)b * TOTAL + loc] = s + bias[loc];
    }
  }
}

extern "C" void kernel_launch(void* const* d_in, const int* in_sizes, int n_in,
                              void* d_out, int out_size, void* d_ws, size_t ws_size,
                              hipStream_t stream) {
  const float* x = (const float*)d_in[0];
  const float* w = (const float*)d_in[1];
  const float* bias = (const float*)d_in[2];
  float* out = (float*)d_out;

  hipLaunchKernelGGL(lc2d_kernel, dim3(OO * HO), dim3(256), 0, stream,
                     x, w, bias, out);
}

// Round 4
// 30.811 us; speedup vs baseline: 1.2185x; 1.0333x over previous
//
#include <hip/hip_runtime.h>

// LocallyConnected2d: out[b,o,ho,wo] = bias[o,ho,wo]
//   + sum_{c,ki,kj} x[b,c,ho+ki,wo+kj] * w[o,c,ho,wo,ki*3+kj]
//
// Round-4: r3 structure + async double-buffered weight staging.
//  - block = (o, ho), 4 waves; wave owns c in [4w, 4w+4). Weight read once.
//  - weight rows staged via __builtin_amdgcn_global_load_lds (width 4):
//    no VGPR round-trip; dest is wave-uniform base + lane*4 (linear layout).
//  - per-wave double buffer: stage(cc+1) issued before compute(cc); the
//    end-of-iteration __syncthreads() drains vmcnt -> buffer ready (m97
//    pattern). 1 barrier per cc (r3 had 2).
//  - x: 12-load batches (b=0..3 / 4..7) -> one latency wait per group;
//    neighbor columns wo+1, wo+2 via ds_bpermute (all loads at col=lane,
//    always in-bounds).

#define BB 8
#define CC 16
#define HH 64
#define WW 64
#define OO 32
#define HO 62
#define WO 62
#define NLOC (HO * WO)    // 3844
#define TOTAL (OO * NLOC) // 123008

__device__ __forceinline__ void async_f32_to_lds(const float* g, float* l) {
  __builtin_amdgcn_global_load_lds((const __attribute__((address_space(1))) void*)g,
                                   (__attribute__((address_space(3))) void*)l,
                                   4, 0, 0);
}

__global__ __launch_bounds__(256) void lc2d_kernel(
    const float* __restrict__ x, const float* __restrict__ weight,
    const float* __restrict__ bias, float* __restrict__ out) {
  // per wave: two 576-float buffers (558 used); buf0 reused for partials
  __shared__ float smem[4 * 2 * 576];

  const int tid  = threadIdx.x;
  const int lane = tid & 63;
  const int wave = tid >> 6;
  const int ho = blockIdx.x % HO;
  const int o  = blockIdx.x / HO;

  float* buf0 = smem + wave * 1152;
  float* buf1 = buf0 + 576;

  const int a1 = ((lane + 1) & 63) << 2;  // bpermute byte addr: pull lane+1
  const int a2 = ((lane + 2) & 63) << 2;  // pull lane+2
  const int lidx = (lane < WO ? lane : WO - 1) * 9;  // clamp: never read unwritten LDS

  const float* wbase = weight + (size_t)(o * CC + wave * 4) * (NLOC * 9)
                              + (size_t)ho * (WO * 9);

  // ---- prologue: stage cc=0 into buf0 (async) ----
#pragma unroll
  for (int j = 0; j < 9; ++j) {
    if (j * 64 + lane < WO * 9)
      async_f32_to_lds(wbase + j * 64 + lane, buf0 + j * 64);
  }

  float acc[BB];
#pragma unroll
  for (int b = 0; b < BB; ++b) acc[b] = 0.0f;

  const float* xw = x + (size_t)(wave * 4) * (HH * WW) + (size_t)ho * WW + lane;

  __syncthreads();  // drains vmcnt: stage(0) landed in LDS

  float* cur = buf0;
  float* nxt = buf1;

  for (int cc = 0; cc < 4; ++cc) {
    // ---- issue stage(cc+1) into the other buffer (overlaps compute) ----
    if (cc < 3) {
      const float* wg = wbase + (size_t)(cc + 1) * (NLOC * 9);
#pragma unroll
      for (int j = 0; j < 9; ++j) {
        if (j * 64 + lane < WO * 9)
          async_f32_to_lds(wg + j * 64 + lane, nxt + j * 64);
      }
    }

    // ---- fragment read from current buffer ----
    float wreg[9];
#pragma unroll
    for (int k = 0; k < 9; ++k) wreg[k] = cur[lidx + k];

    const float* xc = xw + (size_t)cc * (HH * WW);

    // ---- batch 1: b = 0..3 (12 loads, then consume) ----
    float v[4][3];
#pragma unroll
    for (int b = 0; b < 4; ++b) {
      const float* xb = xc + (size_t)b * (CC * HH * WW);
      v[b][0] = xb[0]; v[b][1] = xb[WW]; v[b][2] = xb[2 * WW];
    }
#pragma unroll
    for (int b = 0; b < 4; ++b) {
      float p01 = __int_as_float(__builtin_amdgcn_ds_bpermute(a1, __float_as_int(v[b][0])));
      float p02 = __int_as_float(__builtin_amdgcn_ds_bpermute(a2, __float_as_int(v[b][0])));
      float p11 = __int_as_float(__builtin_amdgcn_ds_bpermute(a1, __float_as_int(v[b][1])));
      float p12 = __int_as_float(__builtin_amdgcn_ds_bpermute(a2, __float_as_int(v[b][1])));
      float p21 = __int_as_float(__builtin_amdgcn_ds_bpermute(a1, __float_as_int(v[b][2])));
      float p22 = __int_as_float(__builtin_amdgcn_ds_bpermute(a2, __float_as_int(v[b][2])));
      acc[b] += v[b][0] * wreg[0] + p01 * wreg[1] + p02 * wreg[2]
              + v[b][1] * wreg[3] + p11 * wreg[4] + p12 * wreg[5]
              + v[b][2] * wreg[6] + p21 * wreg[7] + p22 * wreg[8];
    }

    // ---- batch 2: b = 4..7 ----
#pragma unroll
    for (int b = 0; b < 4; ++b) {
      const float* xb = xc + (size_t)(b + 4) * (CC * HH * WW);
      v[b][0] = xb[0]; v[b][1] = xb[WW]; v[b][2] = xb[2 * WW];
    }
#pragma unroll
    for (int b = 0; b < 4; ++b) {
      float p01 = __int_as_float(__builtin_amdgcn_ds_bpermute(a1, __float_as_int(v[b][0])));
      float p02 = __int_as_float(__builtin_amdgcn_ds_bpermute(a2, __float_as_int(v[b][0])));
      float p11 = __int_as_float(__builtin_amdgcn_ds_bpermute(a1, __float_as_int(v[b][1])));
      float p12 = __int_as_float(__builtin_amdgcn_ds_bpermute(a2, __float_as_int(v[b][1])));
      float p21 = __int_as_float(__builtin_amdgcn_ds_bpermute(a1, __float_as_int(v[b][2])));
      float p22 = __int_as_float(__builtin_amdgcn_ds_bpermute(a2, __float_as_int(v[b][2])));
      acc[b + 4] += v[b][0] * wreg[0] + p01 * wreg[1] + p02 * wreg[2]
                  + v[b][1] * wreg[3] + p11 * wreg[4] + p12 * wreg[5]
                  + v[b][2] * wreg[6] + p21 * wreg[7] + p22 * wreg[8];
    }

    __syncthreads();  // stage(cc+1) drained; safe to read nxt next iter
    float* t = cur; cur = nxt; nxt = t;
  }

  // ---- stash partials into this wave's buf0 ----
#pragma unroll
  for (int b = 0; b < BB; ++b) buf0[lane * 9 + b] = acc[b];
  __syncthreads();

  // ---- reduce 4 wave-partials, add bias, coalesced store ----
  for (int p = tid; p < 512; p += 256) {
    int b = p >> 6;
    int l = p & 63;
    if (l < WO) {
      float s = smem[0 * 1152 + l * 9 + b] + smem[1 * 1152 + l * 9 + b]
              + smem[2 * 1152 + l * 9 + b] + smem[3 * 1152 + l * 9 + b];
      int loc = o * NLOC + ho * WO + l;
      out[(size_t)b * TOTAL + loc] = s + bias[loc];
    }
  }
}

extern "C" void kernel_launch(void* const* d_in, const int* in_sizes, int n_in,
                              void* d_out, int out_size, void* d_ws, size_t ws_size,
                              hipStream_t stream) {
  const float* x = (const float*)d_in[0];
  const float* w = (const float*)d_in[1];
  const float* bias = (const float*)d_in[2];
  float* out = (float*)d_out;

  hipLaunchKernelGGL(lc2d_kernel, dim3(OO * HO), dim3(256), 0, stream,
                     x, w, bias, out);
}

// Round 5
// 26.614 us; speedup vs baseline: 1.4107x; 1.1577x over previous
//
#include <hip/hip_runtime.h>

// LocallyConnected2d: out[b,o,ho,wo] = bias[o,ho,wo]
//   + sum_{c,ki,kj} x[b,c,ho+ki,wo+kj] * w[o,c,ho,wo,ki*3+kj]
//
// Round-5: kill ds_bpermute (DS-pipe bound at ~12-17us/CU in r3/r4).
//  - lane = (q,l): l=lane&15 owns wo = 4l..4l+3; q=lane>>4 owns b = 2q,2q+1.
//    Window cols 4l..4l+5 = one aligned float4 + one float2 -> zero
//    cross-lane exchange.
//  - weights for 4 wo = 36 consecutive floats in LDS = 9x ds_read_b128
//    (16B-aligned: 36 floats = 144B = 9*16B); quadrants broadcast.
//  - weight rows staged once from HBM via global_load_lds, double-buffered
//    (r4 scheme, unchanged); block = (o,ho), 4 waves, wave owns c in
//    [4w,4w+4); cross-wave reduce via LDS.
//  - l=15 edge: float2 clamped in-bounds (col 56); garbage flows only into
//    acc slots wo=62/63 which are discarded at store.

#define BB 8
#define CC 16
#define HH 64
#define WW 64
#define OO 32
#define HO 62
#define WO 62
#define NLOC (HO * WO)    // 3844
#define TOTAL (OO * NLOC) // 123008

typedef float f4 __attribute__((ext_vector_type(4)));
typedef float f2 __attribute__((ext_vector_type(2)));

__device__ __forceinline__ void async_f32_to_lds(const float* g, float* l) {
  __builtin_amdgcn_global_load_lds((const __attribute__((address_space(1))) void*)g,
                                   (__attribute__((address_space(3))) void*)l,
                                   4, 0, 0);
}

__global__ __launch_bounds__(256) void lc2d_kernel(
    const float* __restrict__ x, const float* __restrict__ weight,
    const float* __restrict__ bias, float* __restrict__ out) {
  // per wave: two 576-float weight buffers; buf0 reused for partial stash
  __shared__ float smem[4 * 2 * 576];

  const int tid  = threadIdx.x;
  const int lane = tid & 63;
  const int wave = tid >> 6;
  const int l = lane & 15;   // wo-group: wo = 4l..4l+3
  const int q = lane >> 4;   // b-group:  b  = 2q, 2q+1
  const int ho = blockIdx.x % HO;
  const int o  = blockIdx.x / HO;

  float* buf0 = smem + wave * 1152;
  float* buf1 = buf0 + 576;

  const int colbase = 4 * l;
  const int f2off = (l < 15) ? 4 : -4;  // l=15 reads col 56 (dummy, discarded)

  const float* wbase = weight + (size_t)(o * CC + wave * 4) * (NLOC * 9)
                              + (size_t)ho * (WO * 9);

  // ---- prologue: stage cc=0 into buf0 (async, coalesced, linear dest) ----
#pragma unroll
  for (int j = 0; j < 9; ++j)
    if (j * 64 + lane < WO * 9)
      async_f32_to_lds(wbase + j * 64 + lane, buf0 + j * 64);

  f4 acc[2];
  acc[0] = (f4)0.f;
  acc[1] = (f4)0.f;

  __syncthreads();  // stage(0) landed (vmcnt drained by barrier semantics)

  float* cur = buf0;
  float* nxt = buf1;

  for (int cc = 0; cc < 4; ++cc) {
    // ---- issue stage(cc+1) into other buffer; overlaps compute ----
    if (cc < 3) {
      const float* wg = wbase + (size_t)(cc + 1) * (NLOC * 9);
#pragma unroll
      for (int j = 0; j < 9; ++j)
        if (j * 64 + lane < WO * 9)
          async_f32_to_lds(wg + j * 64 + lane, nxt + j * 64);
    }

    // ---- 36 weights (wo=4l..4l+3 x k=0..8): 9x ds_read_b128 ----
    f4 wq[9];
#pragma unroll
    for (int k = 0; k < 9; ++k)
      wq[k] = *(const f4*)(cur + 36 * l + 4 * k);

    const int c = wave * 4 + cc;

#pragma unroll
    for (int bo = 0; bo < 2; ++bo) {
      const int b = 2 * q + bo;
      const float* xb = x + ((size_t)b * CC + c) * (HH * WW)
                          + (size_t)ho * WW + colbase;
      f4 v4[3];
      f2 v2[3];
#pragma unroll
      for (int r = 0; r < 3; ++r) {
        v4[r] = *(const f4*)(xb + r * WW);
        v2[r] = *(const f2*)(xb + r * WW + f2off);
      }
      // combined window elems e=0..5 -> cols colbase+e
#pragma unroll
      for (int w4 = 0; w4 < 4; ++w4) {
        float s = 0.f;
#pragma unroll
        for (int r = 0; r < 3; ++r) {
#pragma unroll
          for (int j = 0; j < 3; ++j) {
            const int e = w4 + j;                 // 0..5, compile-time
            const int wi = w4 * 9 + r * 3 + j;    // 0..35, compile-time
            const float xv = (e < 4) ? v4[r][e] : v2[r][e - 4];
            s += xv * wq[wi >> 2][wi & 3];
          }
        }
        acc[bo][w4] += s;
      }
    }

    __syncthreads();  // stage(cc+1) drained; cur reads done before overwrite
    float* t = cur; cur = nxt; nxt = t;
  }

  // ---- stash partials: two float4 stores into this wave's buf0 [b][64] ----
#pragma unroll
  for (int bo = 0; bo < 2; ++bo)
    *(f4*)(buf0 + (2 * q + bo) * 64 + colbase) = acc[bo];
  __syncthreads();

  // ---- reduce 4 wave-partials, add bias, coalesced store ----
  for (int p = tid; p < 512; p += 256) {
    const int b  = p >> 6;
    const int wo = p & 63;
    if (wo < WO) {
      float s = smem[0 * 1152 + p] + smem[1 * 1152 + p]
              + smem[2 * 1152 + p] + smem[3 * 1152 + p];
      const int loc = o * NLOC + ho * WO + wo;
      out[(size_t)b * TOTAL + loc] = s + bias[loc];
    }
  }
}

extern "C" void kernel_launch(void* const* d_in, const int* in_sizes, int n_in,
                              void* d_out, int out_size, void* d_ws, size_t ws_size,
                              hipStream_t stream) {
  const float* x = (const float*)d_in[0];
  const float* w = (const float*)d_in[1];
  const float* bias = (const float*)d_in[2];
  float* out = (float*)d_out;

  hipLaunchKernelGGL(lc2d_kernel, dim3(OO * HO), dim3(256), 0, stream,
                     x, w, bias, out);
}